// Round 9
// baseline (158.760 us; speedup 1.0000x reference)
//
#include <hip/hip_runtime.h>
#include <math.h>

// Cone-beam forward projection (TIGRE Ax analogue).
// Volume: [B=2, NZ=96, NY=96, NX=96] f32, ZYX layout (x fastest).
// Output: [B=2, A=48, NV=96, NU=96] f32.
//
// R19 = R18 (z-fast dup-pair layout [y][x][z], wave = 32v x 2u, 4x16B
// gathers, LDS-tiled pack; main 100.2us) + XCD-aware block relabel.
// Evidence: FETCH_SIZE 231MB per dispatch vs 14MB working set = 16x L2
// re-fetch. Default round-robin spreads all 48 angles across the 8 XCDs;
// each 4MB XCD-L2 thrashes across many fans. Relabel (pure index
// bijection, zero numeric change): XCD k gets angles [6k, 6k+6); within
// an XCD the 3 v-tiles of one u-tile (same fan, different z) are
// consecutive, then u-tiles in order (adjacent fans overlap).
// Discriminator: FETCH drop without dur drop => TA-bound floor.
//
// Cost model (validated R10/R13/R14/R17/R18): per wave-sample
// 4 gathers x (16cy addr + lines) overlapped with ~80 VALU instrs.
//
// CORRECTNESS-CRITICAL: reference integrand is DISCONTINUOUS at cube faces.
// Position path replicates the reference's f32 op sequence exactly:
// contract(off), per-sample src + d*t, IEEE sqrt+div, f64-rounded trig.
// Lerp order z->x->y (accepted since R13/R17: value rounding ~1e-6,
// in/out decisions untouched).

#define NZg 96
#define NYg 96
#define NXg 96
#define NVg 96
#define NUg 96
#define NAg 48
#define NSg 96
#define NBg 2
#define NVOX (NZg * NYg * NXg)          // 884736 voxels per batch
#define NRAY1 (NAg * NVg * NUg)         // 442368 rays per batch

typedef float v4f __attribute__((ext_vector_type(4)));  // 16B align

// ---------------- staging: z-fast dup-pair layout via LDS transpose -------
// D[(y*96 + x)*96 + z] = (b0@z, b1@z, b0@z+1, b1@z+1); entry z=95 never
// read (z0<=94). Tile (x,z) 16x16 per y-plane; halo row z0+16.
__global__ __launch_bounds__(256) void pack_b2_zfast_t(
    const float* __restrict__ vol, v4f* __restrict__ D,
    float2* __restrict__ trig) {
    __shared__ float2 tile[17][17];     // [zz][xx], +1 pad vs bank conflicts
    const int y  = blockIdx.x / 36;
    const int t  = blockIdx.x % 36;
    const int z0 = (t / 6) * 16;
    const int x0 = (t % 6) * 16;
    const int tx = threadIdx.x & 15;    // x (read) / z (write) within tile
    const int ty = threadIdx.x >> 4;    // z (read) / x (write) within tile
    // coalesced read: vol is [z][y][x]
    const int rd = ((z0 + ty) * NYg + y) * NXg + (x0 + tx);
    float2 p;
    p.x = vol[rd];
    p.y = vol[rd + NVOX];
    tile[ty][tx] = p;
    if (ty == 0) {                      // z-halo row (z0+16)
        float2 h;
        if (z0 + 16 < NZg) {
            const int rh = ((z0 + 16) * NYg + y) * NXg + (x0 + tx);
            h.x = vol[rh];
            h.y = vol[rh + NVOX];
        } else {
            h.x = 0.0f; h.y = 0.0f;     // never read (z0<=94)
        }
        tile[16][tx] = h;
    }
    __syncthreads();
    // coalesced write: entry (y, x0+ty, z0+tx); consecutive tx -> consec z
    const float2 e0 = tile[tx][ty];
    const float2 e1 = tile[tx + 1][ty];
    v4f e; e.x = e0.x; e.y = e0.y; e.z = e1.x; e.w = e1.y;
    D[(y * NXg + (x0 + ty)) * NZg + (z0 + tx)] = e;
    if (blockIdx.x == 0 && threadIdx.x < NAg) {   // 48-entry trig table
        const float dtheta = 6.2831855f / 48.0f;  // f32(2*pi)/48 (jax linspace)
        const float theta  = (float)threadIdx.x * dtheta;
        float2 cs;
        cs.x = (float)cos((double)theta);
        cs.y = (float)sin((double)theta);
        trig[threadIdx.x] = cs;
    }
}

// ---------------- shared geometry (b-independent) -------------------------
__device__ __forceinline__ void ray_setup_uv(
    int u, int v, float c, float s, float& srcx, float& srcy,
    float& dx, float& dy, float& dz, int& k0, int& k1) {
#pragma clang fp contract(off)
    srcx = 500.0f * c;
    srcy = 500.0f * s;
    const float uu = ((float)u - 47.5f) * 2.0f;
    const float vv = ((float)v - 47.5f) * 2.0f;
    const float pixx = (-500.0f * c) + uu * (-s);
    const float pixy = (-500.0f * s) + uu * c;
    const float pixz = vv;

    const float dx0 = pixx - srcx;
    const float dy0 = pixy - srcy;
    const float dz0 = pixz;
    const float nrm = sqrtf((dx0 * dx0 + dy0 * dy0) + dz0 * dz0);
    dx = dx0 / nrm;
    dy = dy0 / nrm;
    dz = dz0 / nrm;

    const float stepf = (float)1.7320508075688773;   // f32(2R/96)
    const float t0f   = (float)416.8615612366939;    // f32(DSO-R)

    // conservative AABB clip (skip-only; in-loop test is authoritative)
    const float LO = -47.51f, HI = 47.51f;
    float tlo = -1e30f, thi = 1e30f;
    {
        const float o3[3] = {srcx, srcy, 0.0f};
        const float d3[3] = {dx, dy, dz};
        bool empty = false;
        #pragma unroll
        for (int ax = 0; ax < 3; ++ax) {
            const float oo = o3[ax], dd = d3[ax];
            if (fabsf(dd) > 1e-8f) {
                const float inv = 1.0f / dd;
                const float ta = (LO - oo) * inv;
                const float tb = (HI - oo) * inv;
                tlo = fmaxf(tlo, fminf(ta, tb));
                thi = fminf(thi, fmaxf(ta, tb));
            } else if (oo < LO || oo > HI) {
                empty = true;
            }
        }
        if (empty) { tlo = 1.0f; thi = 0.0f; }
    }
    if (thi >= tlo) {
        k0 = (int)floorf((tlo - t0f) / stepf) - 2;
        k1 = (int)ceilf((thi - t0f) / stepf) + 2;
        k0 = max(k0, 0);
        k1 = min(k1, NSg - 1);
    } else {
        k0 = 1; k1 = 0;
    }
}

// ---------------- main: wave = 32v x 2u, z-fast, XCD-grouped --------------
// Grid: 1728 blocks x 256. Relabel (bijective):
//   xcd = blk & 7; j = blk >> 3 (0..215)
//   a  = xcd*6 + j/36          -> each XCD owns 6 consecutive angles
//   rr = j % 36; ut = rr/3; vt = rr%3
//     -> 3 v-tiles of one u-tile (same fan) adjacent, u-tiles in order.
//   wave w covers u = ut*8 + 2w + (lane>>5), v = vt*32 + (lane&31).
__global__ __launch_bounds__(256) void coneproj_zfast3(
    const v4f* __restrict__ D, const float2* __restrict__ trig,
    float* __restrict__ out) {
#pragma clang fp contract(off)
    const int lane = threadIdx.x & 63;
    const int w    = threadIdx.x >> 6;
    const int g    = blockIdx.x;
    const int xcd  = g & 7;
    const int j    = g >> 3;                        // 0..215
    const int a    = xcd * 6 + j / 36;              // uniform per block
    const int rr   = j % 36;
    const int ut   = rr / 3;                        // 0..11
    const int vt   = rr % 3;                        // 0..2
    const int u    = ut * 8 + w * 2 + (lane >> 5);
    const int v    = vt * 32 + (lane & 31);
    const float2 cs = trig[a];

    float srcx, srcy, dx, dy, dz;
    int k0, k1;
    ray_setup_uv(u, v, cs.x, cs.y, srcx, srcy, dx, dy, dz, k0, k1);

    const float stepf = (float)1.7320508075688773;
    const float t0f   = (float)416.8615612366939;

    float acc0 = 0.0f, acc1 = 0.0f;
    for (int k = k0; k <= k1; ++k) {
        const float tk = t0f + ((float)k + 0.5f) * stepf;
        const float ix = (srcx + dx * tk) + 47.5f;
        const float iy = (srcy + dy * tk) + 47.5f;
        const float iz = (dz * tk) + 47.5f;
        if (ix >= 0.0f && ix <= 95.0f &&
            iy >= 0.0f && iy <= 95.0f &&
            iz >= 0.0f && iz <= 95.0f) {
            const int x0 = min((int)ix, NXg - 2);
            const int y0 = min((int)iy, NYg - 2);
            const int z0 = min((int)iz, NZg - 2);
            const float fx = ix - (float)x0;
            const float fy = iy - (float)y0;
            const float fz = iz - (float)z0;
            const int base = (y0 * NXg + x0) * NZg + z0;
            // 4 x 16B aligned loads; each = z-pair (both batches) at one
            // (y,x) corner. Half-waves share the z-window; rows same or
            // x-adjacent => ~12 lines/instruction.
            const v4f r00 = D[base];                     // (y0,x0)
            const v4f r01 = D[base + NZg];               // (y0,x1)
            const v4f r10 = D[base + NXg * NZg];         // (y1,x0)
            const v4f r11 = D[base + NXg * NZg + NZg];   // (y1,x1)
            // batch 0: .x = b0@z0, .z = b0@z1   (lerp order z -> x -> y)
            {
                const float w00 = r00.x + fz * (r00.z - r00.x);
                const float w01 = r01.x + fz * (r01.z - r01.x);
                const float w10 = r10.x + fz * (r10.z - r10.x);
                const float w11 = r11.x + fz * (r11.z - r11.x);
                const float e0  = w00 + fx * (w01 - w00);
                const float e1  = w10 + fx * (w11 - w10);
                acc0 += e0 + fy * (e1 - e0);
            }
            // batch 1: .y = b1@z0, .w = b1@z1
            {
                const float w00 = r00.y + fz * (r00.w - r00.y);
                const float w01 = r01.y + fz * (r01.w - r01.y);
                const float w10 = r10.y + fz * (r10.w - r10.y);
                const float w11 = r11.y + fz * (r11.w - r11.y);
                const float e0  = w00 + fx * (w01 - w00);
                const float e1  = w10 + fx * (w11 - w10);
                acc1 += e0 + fy * (e1 - e0);
            }
        }
    }
    const int oidx = (a * NVg + v) * NUg + u;   // output is [a][v][u]
    out[oidx]         = acc0 * stepf;
    out[oidx + NRAY1] = acc1 * stepf;
}

// ---------------- last-resort: direct 8-gather projector ------------------
__global__ __launch_bounds__(256) void coneproj_direct(
    const float* __restrict__ vol, float* __restrict__ out) {
#pragma clang fp contract(off)
    const int gidx = blockIdx.x * blockDim.x + threadIdx.x;  // includes b
    const int ridx = gidx % NRAY1;
    const int b    = gidx / NRAY1;
    const int u    = ridx % NUg;
    const int v    = (ridx / NUg) % NVg;
    const int a    = ridx / (NUg * NVg);
    const float dtheta = 6.2831855f / 48.0f;
    const float theta  = (float)a * dtheta;
    const float c = (float)cos((double)theta);
    const float s = (float)sin((double)theta);
    float srcx, srcy, dx, dy, dz;
    int k0, k1;
    ray_setup_uv(u, v, c, s, srcx, srcy, dx, dy, dz, k0, k1);

    const float stepf = (float)1.7320508075688773;
    const float t0f   = (float)416.8615612366939;

    const float* __restrict__ volb = vol + (size_t)b * NVOX;

    float acc = 0.0f;
    for (int k = k0; k <= k1; ++k) {
        const float tk = t0f + ((float)k + 0.5f) * stepf;
        const float ix = (srcx + dx * tk) + 47.5f;
        const float iy = (srcy + dy * tk) + 47.5f;
        const float iz = (dz * tk) + 47.5f;
        if (ix >= 0.0f && ix <= 95.0f &&
            iy >= 0.0f && iy <= 95.0f &&
            iz >= 0.0f && iz <= 95.0f) {
            const int x0 = min((int)ix, NXg - 2);
            const int y0 = min((int)iy, NYg - 2);
            const int z0 = min((int)iz, NZg - 2);
            const float fx = ix - (float)x0;
            const float fy = iy - (float)y0;
            const float fz = iz - (float)z0;
            const float* p = volb + ((z0 * NYg + y0) * NXg + x0);
            const float v000 = p[0];
            const float v001 = p[1];
            const float v010 = p[NXg];
            const float v011 = p[NXg + 1];
            const float v100 = p[NYg * NXg];
            const float v101 = p[NYg * NXg + 1];
            const float v110 = p[NYg * NXg + NXg];
            const float v111 = p[NYg * NXg + NXg + 1];
            const float c00 = v000 + fx * (v001 - v000);
            const float c01 = v010 + fx * (v011 - v010);
            const float c10 = v100 + fx * (v101 - v100);
            const float c11 = v110 + fx * (v111 - v110);
            const float c0  = c00 + fy * (c01 - c00);
            const float c1  = c10 + fy * (c11 - c10);
            acc += c0 + fz * (c1 - c0);
        }
    }
    out[gidx] = acc * stepf;
}

extern "C" void kernel_launch(void* const* d_in, const int* in_sizes, int n_in,
                              void* d_out, int out_size, void* d_ws, size_t ws_size,
                              hipStream_t stream) {
    const float* vol = (const float*)d_in[0];
    float* out = (float*)d_out;
    const size_t need_zf = (size_t)NVOX * sizeof(v4f)
                         + (size_t)NAg * sizeof(float2);   // ~14.2 MB
    if (ws_size >= need_zf) {
        v4f*    D    = (v4f*)d_ws;
        float2* trig = (float2*)(D + NVOX);
        pack_b2_zfast_t<<<96 * 36, 256, 0, stream>>>(vol, D, trig);
        coneproj_zfast3<<<NRAY1 / 256, 256, 0, stream>>>(D, trig, out);
    } else {
        coneproj_direct<<<(NBg * NRAY1) / 256, 256, 0, stream>>>(vol, out);
    }
}